// Round 1
// baseline (671.383 us; speedup 1.0000x reference)
//
#include <hip/hip_runtime.h>
#include <hip/hip_bf16.h>
#include <math.h>

#define NB 4
#define NS 2048
#define ND 1024
#define NH 16
#define NHD 64
#define NDFF 4096

typedef __attribute__((ext_vector_type(8))) short bf16x8;
typedef __attribute__((ext_vector_type(4))) float f32x4;
typedef __attribute__((ext_vector_type(4))) short short4v;

static __device__ __forceinline__ short f2b(float f) {
  union { __hip_bfloat16 b; short s; } u;
  u.b = __float2bfloat16(f);
  return u.s;
}

// ---------------- LayerNorm: f32 in -> bf16 out ----------------
__global__ __launch_bounds__(256) void ln_kernel(
    const float* __restrict__ x, const float* __restrict__ g,
    const float* __restrict__ b, short* __restrict__ out) {
  __shared__ float red[8];
  const int row = blockIdx.x;
  const int t = threadIdx.x;
  const float* xr = x + (size_t)row * ND;
  const float4 xv = *(const float4*)(xr + t * 4);
  float s = xv.x + xv.y + xv.z + xv.w;
  float ss = xv.x * xv.x + xv.y * xv.y + xv.z * xv.z + xv.w * xv.w;
#pragma unroll
  for (int m = 32; m >= 1; m >>= 1) {
    s += __shfl_xor(s, m);
    ss += __shfl_xor(ss, m);
  }
  if ((t & 63) == 0) { red[(t >> 6) * 2] = s; red[(t >> 6) * 2 + 1] = ss; }
  __syncthreads();
  s = red[0] + red[2] + red[4] + red[6];
  ss = red[1] + red[3] + red[5] + red[7];
  const float mu = s * (1.0f / ND);
  const float var = ss * (1.0f / ND) - mu * mu;
  const float rs = rsqrtf(var + 1e-5f);
  const float4 gv = *(const float4*)(g + t * 4);
  const float4 bv = *(const float4*)(b + t * 4);
  short o[4];
  o[0] = f2b((xv.x - mu) * rs * gv.x + bv.x);
  o[1] = f2b((xv.y - mu) * rs * gv.y + bv.y);
  o[2] = f2b((xv.z - mu) * rs * gv.z + bv.z);
  o[3] = f2b((xv.w - mu) * rs * gv.w + bv.w);
  *(short4v*)(out + (size_t)row * ND + t * 4) = *(short4v*)o;
}

// ------------- transpose + cast: in f32 (K x N) -> out bf16 (N x K) -------------
__global__ __launch_bounds__(256) void tcast_kernel(
    const float* __restrict__ in, short* __restrict__ out, int K, int N) {
  __shared__ float tile[32][33];
  const int n0 = blockIdx.x * 32, k0 = blockIdx.y * 32;
  const int tx = threadIdx.x & 31, ty = threadIdx.x >> 5;  // 32 x 8
#pragma unroll
  for (int i = 0; i < 32; i += 8)
    tile[ty + i][tx] = in[(size_t)(k0 + ty + i) * N + n0 + tx];
  __syncthreads();
#pragma unroll
  for (int i = 0; i < 32; i += 8)
    out[(size_t)(n0 + ty + i) * K + k0 + tx] = f2b(tile[tx][ty + i]);
}

// ---------------- GEMM: C(MxN) = A(MxK,bf16) * Bt(NxK,bf16)^T + epilogue ----------------
__device__ __forceinline__ void gload16(const void* g, void* l) {
  __builtin_amdgcn_global_load_lds(
      (const __attribute__((address_space(1))) unsigned int*)g,
      (__attribute__((address_space(3))) unsigned int*)l, 16, 0, 0);
}

// EPI: 0 = plain -> bf16 out; 1 = +res -> f32 out; 2 = +bias, gelu -> bf16 out; 3 = +bias+res -> f32 out
template <int EPI>
__global__ __launch_bounds__(256) void gemm_kernel(
    const short* __restrict__ A, const short* __restrict__ Bt,
    float* __restrict__ Cf, short* __restrict__ Cb,
    const float* __restrict__ bias, const float* __restrict__ res,
    int M, int N, int K) {
  __shared__ short Als[128 * 32];
  __shared__ short Bls[128 * 32];
  const int row0 = blockIdx.x * 128, col0 = blockIdx.y * 128;
  const int lane = threadIdx.x & 63, wave = threadIdx.x >> 6;
  const int wr = wave >> 1, wc = wave & 1;
  f32x4 acc[4][4] = {};
  const int sr = lane >> 2;        // row within 16-row chunk
  const int sc = (lane & 3) * 8;   // k within 32
  const int fr = lane & 15, fg = (lane >> 4) * 8;
  for (int kt = 0; kt < K; kt += 32) {
#pragma unroll
    for (int i = 0; i < 2; ++i) {
      const int c = wave * 2 + i;
      gload16(A + (size_t)(row0 + c * 16 + sr) * K + kt + sc, (char*)Als + c * 1024);
      gload16(Bt + (size_t)(col0 + c * 16 + sr) * K + kt + sc, (char*)Bls + c * 1024);
    }
    __syncthreads();
    bf16x8 a[4], b[4];
#pragma unroll
    for (int mi = 0; mi < 4; ++mi)
      a[mi] = *(const bf16x8*)(Als + (wr * 64 + mi * 16 + fr) * 32 + fg);
#pragma unroll
    for (int ni = 0; ni < 4; ++ni)
      b[ni] = *(const bf16x8*)(Bls + (wc * 64 + ni * 16 + fr) * 32 + fg);
#pragma unroll
    for (int mi = 0; mi < 4; ++mi)
#pragma unroll
      for (int ni = 0; ni < 4; ++ni)
        acc[mi][ni] = __builtin_amdgcn_mfma_f32_16x16x32_bf16(a[mi], b[ni], acc[mi][ni], 0, 0, 0);
    __syncthreads();
  }
  const int fq = (lane >> 4) * 4;
#pragma unroll
  for (int mi = 0; mi < 4; ++mi) {
#pragma unroll
    for (int ni = 0; ni < 4; ++ni) {
#pragma unroll
      for (int rr = 0; rr < 4; ++rr) {
        const int grow = row0 + wr * 64 + mi * 16 + fq + rr;
        const int gcol = col0 + wc * 64 + ni * 16 + fr;
        float v = acc[mi][ni][rr];
        if (EPI == 0) {
          Cb[(size_t)grow * N + gcol] = f2b(v);
        } else if (EPI == 1) {
          Cf[(size_t)grow * N + gcol] = v + res[(size_t)grow * N + gcol];
        } else if (EPI == 2) {
          v += bias[gcol];
          v = 0.5f * v * (1.0f + erff(v * 0.70710678118f));
          Cb[(size_t)grow * N + gcol] = f2b(v);
        } else {
          Cf[(size_t)grow * N + gcol] = v + bias[gcol] + res[(size_t)grow * N + gcol];
        }
      }
    }
  }
}

// ---------------- Flash attention (causal), QBLK=KBLK=64 ----------------
__device__ __forceinline__ int swz(int row, int col) {
  return row * 64 + (col ^ ((row & 7) << 3));
}

__global__ __launch_bounds__(256) void attn_kernel(
    const short* __restrict__ q, const short* __restrict__ k,
    const short* __restrict__ v, short* __restrict__ ctx) {
  __shared__ short Qls[64 * 64];
  __shared__ short Kls[64 * 64];
  __shared__ short Vt[64 * 64];
  __shared__ short Pls[4][16 * 64];
  const int qt = blockIdx.x, bh = blockIdx.y;
  const int bb = bh >> 4, hh = bh & 15;
  const int lane = threadIdx.x & 63, wave = threadIdx.x >> 6;
  const int q0 = qt * 64;
  const size_t qbase = ((size_t)bb * NS + q0) * ND + hh * NHD;
  for (int i = threadIdx.x; i < 512; i += 256) {
    const int rr = i >> 3, cc = (i & 7) * 8;
    *(bf16x8*)&Qls[swz(rr, cc)] = *(const bf16x8*)&q[qbase + (size_t)rr * ND + cc];
  }
  f32x4 acc_o[4] = {};
  float m_run[4], l_run[4];
#pragma unroll
  for (int r = 0; r < 4; ++r) { m_run[r] = -INFINITY; l_run[r] = 0.f; }
  const int fr = lane & 15, fg = lane >> 4;
  for (int jt = 0; jt <= qt; ++jt) {
    const int k0 = jt * 64;
    const size_t kbase = ((size_t)bb * NS + k0) * ND + hh * NHD;
    __syncthreads();
    for (int i = threadIdx.x; i < 512; i += 256) {
      const int rr = i >> 3, cc = (i & 7) * 8;
      *(bf16x8*)&Kls[swz(rr, cc)] = *(const bf16x8*)&k[kbase + (size_t)rr * ND + cc];
      const bf16x8 vv = *(const bf16x8*)&v[kbase + (size_t)rr * ND + cc];
#pragma unroll
      for (int j = 0; j < 8; ++j) Vt[swz(cc + j, rr)] = vv[j];
    }
    __syncthreads();
    f32x4 s[4] = {};
#pragma unroll
    for (int kk = 0; kk < 2; ++kk) {
      const bf16x8 af = *(const bf16x8*)&Qls[swz(wave * 16 + fr, kk * 32 + fg * 8)];
#pragma unroll
      for (int ni = 0; ni < 4; ++ni) {
        const bf16x8 bf = *(const bf16x8*)&Kls[swz(ni * 16 + fr, kk * 32 + fg * 8)];
        s[ni] = __builtin_amdgcn_mfma_f32_16x16x32_bf16(af, bf, s[ni], 0, 0, 0);
      }
    }
    float mt[4] = {-INFINITY, -INFINITY, -INFINITY, -INFINITY};
    const bool diag = (jt == qt);
#pragma unroll
    for (int ni = 0; ni < 4; ++ni) {
#pragma unroll
      for (int rr = 0; rr < 4; ++rr) {
        float val = s[ni][rr] * 0.125f;
        if (diag && (ni * 16 + fr > wave * 16 + fg * 4 + rr)) val = -INFINITY;
        s[ni][rr] = val;
        mt[rr] = fmaxf(mt[rr], val);
      }
    }
#pragma unroll
    for (int m = 1; m < 16; m <<= 1) {
#pragma unroll
      for (int rr = 0; rr < 4; ++rr) mt[rr] = fmaxf(mt[rr], __shfl_xor(mt[rr], m));
    }
    float sc_f[4];
#pragma unroll
    for (int rr = 0; rr < 4; ++rr) {
      const float mn = fmaxf(m_run[rr], mt[rr]);
      sc_f[rr] = __expf(m_run[rr] - mn);
      m_run[rr] = mn;
    }
    float lt[4] = {0.f, 0.f, 0.f, 0.f};
#pragma unroll
    for (int ni = 0; ni < 4; ++ni) {
#pragma unroll
      for (int rr = 0; rr < 4; ++rr) {
        const float p = __expf(s[ni][rr] - m_run[rr]);
        s[ni][rr] = p;
        lt[rr] += p;
      }
    }
#pragma unroll
    for (int m = 1; m < 16; m <<= 1) {
#pragma unroll
      for (int rr = 0; rr < 4; ++rr) lt[rr] += __shfl_xor(lt[rr], m);
    }
#pragma unroll
    for (int rr = 0; rr < 4; ++rr) l_run[rr] = l_run[rr] * sc_f[rr] + lt[rr];
#pragma unroll
    for (int di = 0; di < 4; ++di) {
#pragma unroll
      for (int rr = 0; rr < 4; ++rr) acc_o[di][rr] *= sc_f[rr];
    }
#pragma unroll
    for (int ni = 0; ni < 4; ++ni) {
#pragma unroll
      for (int rr = 0; rr < 4; ++rr)
        Pls[wave][swz(fg * 4 + rr, ni * 16 + fr)] = f2b(s[ni][rr]);
    }
#pragma unroll
    for (int kk = 0; kk < 2; ++kk) {
      const bf16x8 pf = *(const bf16x8*)&Pls[wave][swz(fr, kk * 32 + fg * 8)];
#pragma unroll
      for (int di = 0; di < 4; ++di) {
        const bf16x8 vf = *(const bf16x8*)&Vt[swz(di * 16 + fr, kk * 32 + fg * 8)];
        acc_o[di] = __builtin_amdgcn_mfma_f32_16x16x32_bf16(pf, vf, acc_o[di], 0, 0, 0);
      }
    }
  }
  const size_t obase = ((size_t)bb * NS + q0) * ND + hh * NHD;
#pragma unroll
  for (int di = 0; di < 4; ++di) {
#pragma unroll
    for (int rr = 0; rr < 4; ++rr) {
      const int row = wave * 16 + fg * 4 + rr;
      const int col = di * 16 + fr;
      ctx[obase + (size_t)row * ND + col] = f2b(acc_o[di][rr] / l_run[rr]);
    }
  }
}

extern "C" void kernel_launch(void* const* d_in, const int* in_sizes, int n_in,
                              void* d_out, int out_size, void* d_ws, size_t ws_size,
                              hipStream_t stream) {
  (void)in_sizes; (void)n_in; (void)out_size; (void)ws_size;
  const float* x     = (const float*)d_in[0];
  const float* ln1_g = (const float*)d_in[1];
  const float* ln1_b = (const float*)d_in[2];
  const float* Wq    = (const float*)d_in[3];
  const float* Wk    = (const float*)d_in[4];
  const float* Wv    = (const float*)d_in[5];
  const float* Wo    = (const float*)d_in[6];
  const float* ln2_g = (const float*)d_in[7];
  const float* ln2_b = (const float*)d_in[8];
  const float* W1    = (const float*)d_in[9];
  const float* b1    = (const float*)d_in[10];
  const float* W2    = (const float*)d_in[11];
  const float* b2    = (const float*)d_in[12];
  float* out = (float*)d_out;

  char* ws = (char*)d_ws;
  const size_t MiB = 1024 * 1024;
  short* wqT = (short*)(ws + 0 * MiB);    // 2 MiB
  short* wkT = (short*)(ws + 2 * MiB);    // 2 MiB
  short* wvT = (short*)(ws + 4 * MiB);    // 2 MiB
  short* woT = (short*)(ws + 6 * MiB);    // 2 MiB
  short* w1T = (short*)(ws + 8 * MiB);    // 8 MiB
  short* w2T = (short*)(ws + 16 * MiB);   // 8 MiB
  short* h   = (short*)(ws + 24 * MiB);   // 16 MiB (LN1 out, later LN2 out)
  short* qb  = (short*)(ws + 40 * MiB);   // 16 MiB
  short* kb  = (short*)(ws + 56 * MiB);   // 16 MiB
  short* vb  = (short*)(ws + 72 * MiB);   // 16 MiB
  short* ctx = (short*)(ws + 88 * MiB);   // 16 MiB
  short* hff = (short*)(ws + 40 * MiB);   // 64 MiB, reuses q/k/v/ctx after attention
  float* x1  = (float*)(ws + 104 * MiB);  // 32 MiB; end = 136 MiB

  // weight transpose-casts (B^T layout, bf16)
  tcast_kernel<<<dim3(32, 32), 256, 0, stream>>>(Wq, wqT, 1024, 1024);
  tcast_kernel<<<dim3(32, 32), 256, 0, stream>>>(Wk, wkT, 1024, 1024);
  tcast_kernel<<<dim3(32, 32), 256, 0, stream>>>(Wv, wvT, 1024, 1024);
  tcast_kernel<<<dim3(32, 32), 256, 0, stream>>>(Wo, woT, 1024, 1024);
  tcast_kernel<<<dim3(128, 32), 256, 0, stream>>>(W1, w1T, 1024, 4096);
  tcast_kernel<<<dim3(32, 128), 256, 0, stream>>>(W2, w2T, 4096, 1024);

  // LN1
  ln_kernel<<<8192, 256, 0, stream>>>(x, ln1_g, ln1_b, h);

  // QKV projections
  gemm_kernel<0><<<dim3(64, 8), 256, 0, stream>>>(h, wqT, nullptr, qb, nullptr, nullptr, 8192, 1024, 1024);
  gemm_kernel<0><<<dim3(64, 8), 256, 0, stream>>>(h, wkT, nullptr, kb, nullptr, nullptr, 8192, 1024, 1024);
  gemm_kernel<0><<<dim3(64, 8), 256, 0, stream>>>(h, wvT, nullptr, vb, nullptr, nullptr, 8192, 1024, 1024);

  // causal flash attention
  attn_kernel<<<dim3(32, 64), 256, 0, stream>>>(qb, kb, vb, ctx);

  // out-proj + residual -> x1 (f32)
  gemm_kernel<1><<<dim3(64, 8), 256, 0, stream>>>(ctx, woT, x1, nullptr, nullptr, x, 8192, 1024, 1024);

  // LN2
  ln_kernel<<<8192, 256, 0, stream>>>(x1, ln2_g, ln2_b, h);

  // FFN
  gemm_kernel<2><<<dim3(64, 32), 256, 0, stream>>>(h, w1T, nullptr, hff, b1, nullptr, 8192, 4096, 1024);
  gemm_kernel<3><<<dim3(64, 8), 256, 0, stream>>>(hff, w2T, out, nullptr, b2, x1, 8192, 1024, 4096);
}

// Round 2
// 490.397 us; speedup vs baseline: 1.3691x; 1.3691x over previous
//
#include <hip/hip_runtime.h>
#include <hip/hip_bf16.h>
#include <math.h>

#define NB 4
#define NS 2048
#define ND 1024
#define NH 16
#define NHD 64
#define NDFF 4096

typedef __attribute__((ext_vector_type(8))) short bf16x8;
typedef __attribute__((ext_vector_type(4))) float f32x4;
typedef __attribute__((ext_vector_type(4))) short short4v;

static __device__ __forceinline__ short f2b(float f) {
  union { __hip_bfloat16 b; short s; } u;
  u.b = __float2bfloat16(f);
  return u.s;
}

// ---------------- LayerNorm: f32 in -> bf16 out ----------------
__global__ __launch_bounds__(256) void ln_kernel(
    const float* __restrict__ x, const float* __restrict__ g,
    const float* __restrict__ b, short* __restrict__ out) {
  __shared__ float red[8];
  const int row = blockIdx.x;
  const int t = threadIdx.x;
  const float* xr = x + (size_t)row * ND;
  const float4 xv = *(const float4*)(xr + t * 4);
  float s = xv.x + xv.y + xv.z + xv.w;
  float ss = xv.x * xv.x + xv.y * xv.y + xv.z * xv.z + xv.w * xv.w;
#pragma unroll
  for (int m = 32; m >= 1; m >>= 1) {
    s += __shfl_xor(s, m);
    ss += __shfl_xor(ss, m);
  }
  if ((t & 63) == 0) { red[(t >> 6) * 2] = s; red[(t >> 6) * 2 + 1] = ss; }
  __syncthreads();
  s = red[0] + red[2] + red[4] + red[6];
  ss = red[1] + red[3] + red[5] + red[7];
  const float mu = s * (1.0f / ND);
  const float var = ss * (1.0f / ND) - mu * mu;
  const float rs = rsqrtf(var + 1e-5f);
  const float4 gv = *(const float4*)(g + t * 4);
  const float4 bv = *(const float4*)(b + t * 4);
  short o[4];
  o[0] = f2b((xv.x - mu) * rs * gv.x + bv.x);
  o[1] = f2b((xv.y - mu) * rs * gv.y + bv.y);
  o[2] = f2b((xv.z - mu) * rs * gv.z + bv.z);
  o[3] = f2b((xv.w - mu) * rs * gv.w + bv.w);
  *(short4v*)(out + (size_t)row * ND + t * 4) = *(short4v*)o;
}

// ------------- transpose + cast: in f32 (K x N) -> out bf16 (N x K) -------------
__global__ __launch_bounds__(256) void tcast_kernel(
    const float* __restrict__ in, short* __restrict__ out, int K, int N) {
  __shared__ float tile[32][33];
  const int n0 = blockIdx.x * 32, k0 = blockIdx.y * 32;
  const int tx = threadIdx.x & 31, ty = threadIdx.x >> 5;  // 32 x 8
#pragma unroll
  for (int i = 0; i < 32; i += 8)
    tile[ty + i][tx] = in[(size_t)(k0 + ty + i) * N + n0 + tx];
  __syncthreads();
#pragma unroll
  for (int i = 0; i < 32; i += 8)
    out[(size_t)(n0 + ty + i) * K + k0 + tx] = f2b(tile[tx][ty + i]);
}

// ------------- V transpose: vb[b][s][h][d] bf16 -> vt[b*H+h][d][s] bf16 -------------
__global__ __launch_bounds__(256) void vtrans_kernel(
    const short* __restrict__ in, short* __restrict__ out) {
  __shared__ short tile[64][72];
  const int s0 = blockIdx.x * 64, bh = blockIdx.y;
  const int bb = bh >> 4, hh = bh & 15;
  const int rr = threadIdx.x >> 3, cc = (threadIdx.x & 7) * 8;  // rr 0..31
#pragma unroll
  for (int it = 0; it < 2; ++it) {
    const int r = rr + it * 32;
    *(bf16x8*)&tile[r][cc] =
        *(const bf16x8*)&in[((size_t)(bb * NS + s0 + r)) * ND + hh * NHD + cc];
  }
  __syncthreads();
  const size_t ob = (size_t)bh * NHD * NS;
#pragma unroll
  for (int it = 0; it < 2; ++it) {
    const int d = rr + it * 32;
    short o[8];
#pragma unroll
    for (int j = 0; j < 8; ++j) o[j] = tile[cc + j][d];
    *(bf16x8*)&out[ob + (size_t)d * NS + s0 + cc] = *(bf16x8*)o;
  }
}

// ---------------- GEMM: C(MxN) = A(MxK,bf16) * Bt(NxK,bf16)^T + epilogue ----------------
__device__ __forceinline__ void gload16(const void* g, void* l) {
  __builtin_amdgcn_global_load_lds(
      (const __attribute__((address_space(1))) unsigned int*)g,
      (__attribute__((address_space(3))) unsigned int*)l, 16, 0, 0);
}

// EPI: 0 = plain -> bf16 out; 1 = +res -> f32 out; 2 = +bias, gelu -> bf16 out; 3 = +bias+res -> f32 out
template <int EPI>
__global__ __launch_bounds__(256) void gemm_kernel(
    const short* __restrict__ A, const short* __restrict__ Bt,
    float* __restrict__ Cf, short* __restrict__ Cb,
    const float* __restrict__ bias, const float* __restrict__ res,
    int M, int N, int K) {
  __shared__ short Als[128 * 32];
  __shared__ short Bls[128 * 32];
  const int row0 = blockIdx.x * 128, col0 = blockIdx.y * 128;
  const int lane = threadIdx.x & 63, wave = threadIdx.x >> 6;
  const int wr = wave >> 1, wc = wave & 1;
  f32x4 acc[4][4] = {};
  const int sr = lane >> 2;        // row within 16-row chunk
  const int sc = (lane & 3) * 8;   // k within 32
  const int fr = lane & 15, fg = (lane >> 4) * 8;
  for (int kt = 0; kt < K; kt += 32) {
#pragma unroll
    for (int i = 0; i < 2; ++i) {
      const int c = wave * 2 + i;
      gload16(A + (size_t)(row0 + c * 16 + sr) * K + kt + sc, (char*)Als + c * 1024);
      gload16(Bt + (size_t)(col0 + c * 16 + sr) * K + kt + sc, (char*)Bls + c * 1024);
    }
    __syncthreads();
    bf16x8 a[4], b[4];
#pragma unroll
    for (int mi = 0; mi < 4; ++mi)
      a[mi] = *(const bf16x8*)(Als + (wr * 64 + mi * 16 + fr) * 32 + fg);
#pragma unroll
    for (int ni = 0; ni < 4; ++ni)
      b[ni] = *(const bf16x8*)(Bls + (wc * 64 + ni * 16 + fr) * 32 + fg);
#pragma unroll
    for (int mi = 0; mi < 4; ++mi)
#pragma unroll
      for (int ni = 0; ni < 4; ++ni)
        acc[mi][ni] = __builtin_amdgcn_mfma_f32_16x16x32_bf16(a[mi], b[ni], acc[mi][ni], 0, 0, 0);
    __syncthreads();
  }
  const int fq = (lane >> 4) * 4;
#pragma unroll
  for (int mi = 0; mi < 4; ++mi) {
#pragma unroll
    for (int ni = 0; ni < 4; ++ni) {
#pragma unroll
      for (int rr = 0; rr < 4; ++rr) {
        const int grow = row0 + wr * 64 + mi * 16 + fq + rr;
        const int gcol = col0 + wc * 64 + ni * 16 + fr;
        float v = acc[mi][ni][rr];
        if (EPI == 0) {
          Cb[(size_t)grow * N + gcol] = f2b(v);
        } else if (EPI == 1) {
          Cf[(size_t)grow * N + gcol] = v + res[(size_t)grow * N + gcol];
        } else if (EPI == 2) {
          v += bias[gcol];
          v = 0.5f * v * (1.0f + erff(v * 0.70710678118f));
          Cb[(size_t)grow * N + gcol] = f2b(v);
        } else {
          Cf[(size_t)grow * N + gcol] = v + bias[gcol] + res[(size_t)grow * N + gcol];
        }
      }
    }
  }
}

// ---------------- Flash attention (causal), paired q-tiles, QBLK=KBLK=64 ----------------
__device__ __forceinline__ int swz(int row, int col) {
  return row * 64 + (col ^ ((row & 7) << 3));
}

__global__ __launch_bounds__(256, 4) void attn_kernel(
    const short* __restrict__ q, const short* __restrict__ k,
    const short* __restrict__ vt, short* __restrict__ ctx) {
  __shared__ short Kls[64 * 64];           // [k_local][d], XOR-swizzled
  __shared__ short Vls[64 * 64];           // [d][k_local], XOR-swizzled
  __shared__ short Pls[4][16 * 68];        // per-wave P, pad-68 (2-way writes, cf b64 reads)
  const int bid = blockIdx.x;
  const int xcd = bid & 7, idx = bid >> 3;
  const int bh = xcd * 8 + (idx & 7);      // co-locate each (b,h)'s 16 blocks on one XCD
  const int qp = idx >> 3;                 // 0..15
  const int bb = bh >> 4, hh = bh & 15;
  const int lane = threadIdx.x & 63, wave = threadIdx.x >> 6;
  const int fr = lane & 15, fg = lane >> 4;
  const int qt[2] = {qp, 31 - qp};         // paired q-tiles: constant 33 tile-computes/block

  // Q fragments live in registers (loaded once)
  bf16x8 qf[2][2];
#pragma unroll
  for (int hf = 0; hf < 2; ++hf) {
    const size_t qb = ((size_t)bb * NS + qt[hf] * 64 + wave * 16 + fr) * ND + hh * NHD;
    qf[hf][0] = *(const bf16x8*)&q[qb + fg * 8];
    qf[hf][1] = *(const bf16x8*)&q[qb + 32 + fg * 8];
  }

  f32x4 acc_o[2][4] = {};
  float m_run[2][4], l_run[2][4];
#pragma unroll
  for (int hf = 0; hf < 2; ++hf)
#pragma unroll
    for (int r = 0; r < 4; ++r) { m_run[hf][r] = -INFINITY; l_run[hf][r] = 0.f; }

  // staging constants: pre-swizzled global source so linear gload_lds yields swz layout
  const int gcol = ((lane & 7) ^ (lane >> 3)) * 8;
  const int grow = lane >> 3;
  const int nkt = 32 - qp;

  for (int jt = 0; jt < nkt; ++jt) {
    const int k0 = jt * 64;
    __syncthreads();  // all waves done reading previous tile
#pragma unroll
    for (int i = 0; i < 2; ++i) {
      const int c = wave * 2 + i;
      const int r = c * 8 + grow;
      gload16(k + ((size_t)bb * NS + k0 + r) * ND + hh * NHD + gcol, (char*)Kls + c * 1024);
      gload16(vt + ((size_t)bh * NHD + r) * NS + k0 + gcol, (char*)Vls + c * 1024);
    }
    __syncthreads();  // staged tile visible (syncthreads drains vmcnt)

#pragma unroll
    for (int hf = 0; hf < 2; ++hf) {
      if (hf == 0 && jt > qp) continue;  // half A finished (uniform branch)
      const bool diag = (jt == qt[hf]);
      f32x4 s[4] = {};
#pragma unroll
      for (int kk = 0; kk < 2; ++kk) {
        const bf16x8 af = qf[hf][kk];
#pragma unroll
        for (int ni = 0; ni < 4; ++ni) {
          const bf16x8 bf = *(const bf16x8*)&Kls[swz(ni * 16 + fr, kk * 32 + fg * 8)];
          s[ni] = __builtin_amdgcn_mfma_f32_16x16x32_bf16(af, bf, s[ni], 0, 0, 0);
        }
      }
      float mt[4] = {-INFINITY, -INFINITY, -INFINITY, -INFINITY};
#pragma unroll
      for (int ni = 0; ni < 4; ++ni) {
#pragma unroll
        for (int rr = 0; rr < 4; ++rr) {
          float val = s[ni][rr] * 0.125f;
          if (diag && (ni * 16 + fr > wave * 16 + fg * 4 + rr)) val = -INFINITY;
          s[ni][rr] = val;
          mt[rr] = fmaxf(mt[rr], val);
        }
      }
#pragma unroll
      for (int m = 1; m < 16; m <<= 1) {
#pragma unroll
        for (int rr = 0; rr < 4; ++rr) mt[rr] = fmaxf(mt[rr], __shfl_xor(mt[rr], m));
      }
      float sc_f[4];
#pragma unroll
      for (int rr = 0; rr < 4; ++rr) {
        const float mn = fmaxf(m_run[hf][rr], mt[rr]);
        sc_f[rr] = __expf(m_run[hf][rr] - mn);
        m_run[hf][rr] = mn;
      }
      float lt[4] = {0.f, 0.f, 0.f, 0.f};
#pragma unroll
      for (int ni = 0; ni < 4; ++ni) {
#pragma unroll
        for (int rr = 0; rr < 4; ++rr) {
          const float p = __expf(s[ni][rr] - m_run[hf][rr]);
          s[ni][rr] = p;
          lt[rr] += p;
        }
      }
#pragma unroll
      for (int m = 1; m < 16; m <<= 1) {
#pragma unroll
        for (int rr = 0; rr < 4; ++rr) lt[rr] += __shfl_xor(lt[rr], m);
      }
#pragma unroll
      for (int rr = 0; rr < 4; ++rr) l_run[hf][rr] = l_run[hf][rr] * sc_f[rr] + lt[rr];
#pragma unroll
      for (int di = 0; di < 4; ++di) {
#pragma unroll
        for (int rr = 0; rr < 4; ++rr) acc_o[hf][di][rr] *= sc_f[rr];
      }
#pragma unroll
      for (int ni = 0; ni < 4; ++ni) {
#pragma unroll
        for (int rr = 0; rr < 4; ++rr)
          Pls[wave][(fg * 4 + rr) * 68 + ni * 16 + fr] = f2b(s[ni][rr]);
      }
#pragma unroll
      for (int kk = 0; kk < 2; ++kk) {
        const short4v p0 = *(const short4v*)&Pls[wave][fr * 68 + kk * 32 + fg * 8];
        const short4v p1 = *(const short4v*)&Pls[wave][fr * 68 + kk * 32 + fg * 8 + 4];
        const bf16x8 pf = __builtin_shufflevector(p0, p1, 0, 1, 2, 3, 4, 5, 6, 7);
#pragma unroll
        for (int di = 0; di < 4; ++di) {
          const bf16x8 vf = *(const bf16x8*)&Vls[swz(di * 16 + fr, kk * 32 + fg * 8)];
          acc_o[hf][di] = __builtin_amdgcn_mfma_f32_16x16x32_bf16(pf, vf, acc_o[hf][di], 0, 0, 0);
        }
      }
    }
  }

#pragma unroll
  for (int hf = 0; hf < 2; ++hf) {
    const size_t ob = ((size_t)bb * NS + qt[hf] * 64) * ND + hh * NHD;
#pragma unroll
    for (int di = 0; di < 4; ++di) {
#pragma unroll
      for (int rr = 0; rr < 4; ++rr) {
        const int row = wave * 16 + fg * 4 + rr;
        const int col = di * 16 + fr;
        ctx[ob + (size_t)row * ND + col] = f2b(acc_o[hf][di][rr] / l_run[hf][rr]);
      }
    }
  }
}

extern "C" void kernel_launch(void* const* d_in, const int* in_sizes, int n_in,
                              void* d_out, int out_size, void* d_ws, size_t ws_size,
                              hipStream_t stream) {
  (void)in_sizes; (void)n_in; (void)out_size; (void)ws_size;
  const float* x     = (const float*)d_in[0];
  const float* ln1_g = (const float*)d_in[1];
  const float* ln1_b = (const float*)d_in[2];
  const float* Wq    = (const float*)d_in[3];
  const float* Wk    = (const float*)d_in[4];
  const float* Wv    = (const float*)d_in[5];
  const float* Wo    = (const float*)d_in[6];
  const float* ln2_g = (const float*)d_in[7];
  const float* ln2_b = (const float*)d_in[8];
  const float* W1    = (const float*)d_in[9];
  const float* b1    = (const float*)d_in[10];
  const float* W2    = (const float*)d_in[11];
  const float* b2    = (const float*)d_in[12];
  float* out = (float*)d_out;

  char* ws = (char*)d_ws;
  const size_t MiB = 1024 * 1024;
  short* wqT = (short*)(ws + 0 * MiB);    // 2 MiB
  short* wkT = (short*)(ws + 2 * MiB);    // 2 MiB
  short* wvT = (short*)(ws + 4 * MiB);    // 2 MiB
  short* woT = (short*)(ws + 6 * MiB);    // 2 MiB
  short* w1T = (short*)(ws + 8 * MiB);    // 8 MiB
  short* w2T = (short*)(ws + 16 * MiB);   // 8 MiB
  short* h   = (short*)(ws + 24 * MiB);   // 16 MiB (LN1 out, later LN2 out)
  short* qb  = (short*)(ws + 40 * MiB);   // 16 MiB
  short* kb  = (short*)(ws + 56 * MiB);   // 16 MiB
  short* vb  = (short*)(ws + 72 * MiB);   // 16 MiB (dead after vtrans)
  short* ctx = (short*)(ws + 72 * MiB);   // 16 MiB (reuses vb after vtrans)
  short* vt  = (short*)(ws + 88 * MiB);   // 16 MiB (V^T, dead after attn)
  short* hff = (short*)(ws + 40 * MiB);   // 64 MiB, reuses q/k/ctx/vt after attention
  float* x1  = (float*)(ws + 104 * MiB);  // 32 MiB; end = 136 MiB

  // weight transpose-casts (B^T layout, bf16)
  tcast_kernel<<<dim3(32, 32), 256, 0, stream>>>(Wq, wqT, 1024, 1024);
  tcast_kernel<<<dim3(32, 32), 256, 0, stream>>>(Wk, wkT, 1024, 1024);
  tcast_kernel<<<dim3(32, 32), 256, 0, stream>>>(Wv, wvT, 1024, 1024);
  tcast_kernel<<<dim3(32, 32), 256, 0, stream>>>(Wo, woT, 1024, 1024);
  tcast_kernel<<<dim3(128, 32), 256, 0, stream>>>(W1, w1T, 1024, 4096);
  tcast_kernel<<<dim3(32, 128), 256, 0, stream>>>(W2, w2T, 4096, 1024);

  // LN1
  ln_kernel<<<8192, 256, 0, stream>>>(x, ln1_g, ln1_b, h);

  // QKV projections (V first so vtrans can start)
  gemm_kernel<0><<<dim3(64, 8), 256, 0, stream>>>(h, wvT, nullptr, vb, nullptr, nullptr, 8192, 1024, 1024);
  vtrans_kernel<<<dim3(32, 64), 256, 0, stream>>>(vb, vt);
  gemm_kernel<0><<<dim3(64, 8), 256, 0, stream>>>(h, wqT, nullptr, qb, nullptr, nullptr, 8192, 1024, 1024);
  gemm_kernel<0><<<dim3(64, 8), 256, 0, stream>>>(h, wkT, nullptr, kb, nullptr, nullptr, 8192, 1024, 1024);

  // causal flash attention (paired q-tiles, XCD-colocated heads)
  attn_kernel<<<1024, 256, 0, stream>>>(qb, kb, vt, ctx);

  // out-proj + residual -> x1 (f32)
  gemm_kernel<1><<<dim3(64, 8), 256, 0, stream>>>(ctx, woT, x1, nullptr, nullptr, x, 8192, 1024, 1024);

  // LN2
  ln_kernel<<<8192, 256, 0, stream>>>(x1, ln2_g, ln2_b, h);

  // FFN
  gemm_kernel<2><<<dim3(64, 32), 256, 0, stream>>>(h, w1T, nullptr, hff, b1, nullptr, 8192, 4096, 1024);
  gemm_kernel<3><<<dim3(64, 8), 256, 0, stream>>>(hff, w2T, out, nullptr, b2, x1, 8192, 1024, 4096);
}

// Round 3
// 438.704 us; speedup vs baseline: 1.5304x; 1.1178x over previous
//
#include <hip/hip_runtime.h>
#include <hip/hip_bf16.h>
#include <math.h>

#define NB 4
#define NS 2048
#define ND 1024
#define NH 16
#define NHD 64
#define NDFF 4096
#define QKS 3072   // packed qkv row stride

typedef __attribute__((ext_vector_type(8))) short bf16x8;
typedef __attribute__((ext_vector_type(4))) float f32x4;
typedef __attribute__((ext_vector_type(4))) short short4v;

static __device__ __forceinline__ short f2b(float f) {
  union { __hip_bfloat16 b; short s; } u;
  u.b = __float2bfloat16(f);
  return u.s;
}

// ---------------- LayerNorm: f32 in -> bf16 out ----------------
__global__ __launch_bounds__(256) void ln_kernel(
    const float* __restrict__ x, const float* __restrict__ g,
    const float* __restrict__ b, short* __restrict__ out) {
  __shared__ float red[8];
  const int row = blockIdx.x;
  const int t = threadIdx.x;
  const float* xr = x + (size_t)row * ND;
  const float4 xv = *(const float4*)(xr + t * 4);
  float s = xv.x + xv.y + xv.z + xv.w;
  float ss = xv.x * xv.x + xv.y * xv.y + xv.z * xv.z + xv.w * xv.w;
#pragma unroll
  for (int m = 32; m >= 1; m >>= 1) {
    s += __shfl_xor(s, m);
    ss += __shfl_xor(ss, m);
  }
  if ((t & 63) == 0) { red[(t >> 6) * 2] = s; red[(t >> 6) * 2 + 1] = ss; }
  __syncthreads();
  s = red[0] + red[2] + red[4] + red[6];
  ss = red[1] + red[3] + red[5] + red[7];
  const float mu = s * (1.0f / ND);
  const float var = ss * (1.0f / ND) - mu * mu;
  const float rs = rsqrtf(var + 1e-5f);
  const float4 gv = *(const float4*)(g + t * 4);
  const float4 bv = *(const float4*)(b + t * 4);
  short o[4];
  o[0] = f2b((xv.x - mu) * rs * gv.x + bv.x);
  o[1] = f2b((xv.y - mu) * rs * gv.y + bv.y);
  o[2] = f2b((xv.z - mu) * rs * gv.z + bv.z);
  o[3] = f2b((xv.w - mu) * rs * gv.w + bv.w);
  *(short4v*)(out + (size_t)row * ND + t * 4) = *(short4v*)o;
}

// ------------- transpose + cast: in f32 (K x N) -> out bf16 (N x K) -------------
__global__ __launch_bounds__(256) void tcast_kernel(
    const float* __restrict__ in, short* __restrict__ out, int K, int N) {
  __shared__ float tile[32][33];
  const int n0 = blockIdx.x * 32, k0 = blockIdx.y * 32;
  const int tx = threadIdx.x & 31, ty = threadIdx.x >> 5;  // 32 x 8
#pragma unroll
  for (int i = 0; i < 32; i += 8)
    tile[ty + i][tx] = in[(size_t)(k0 + ty + i) * N + n0 + tx];
  __syncthreads();
#pragma unroll
  for (int i = 0; i < 32; i += 8)
    out[(size_t)(n0 + ty + i) * K + k0 + tx] = f2b(tile[tx][ty + i]);
}

// ------------- V transpose: packed qkv (v at col 2048) -> vt[b*H+h][d][s] bf16 -------------
__global__ __launch_bounds__(256) void vtrans_kernel(
    const short* __restrict__ in, short* __restrict__ out) {
  __shared__ short tile[64][72];
  const int s0 = blockIdx.x * 64, bh = blockIdx.y;
  const int bb = bh >> 4, hh = bh & 15;
  const int rr = threadIdx.x >> 3, cc = (threadIdx.x & 7) * 8;  // rr 0..31
#pragma unroll
  for (int it = 0; it < 2; ++it) {
    const int r = rr + it * 32;
    *(bf16x8*)&tile[r][cc] =
        *(const bf16x8*)&in[((size_t)(bb * NS + s0 + r)) * QKS + 2048 + hh * NHD + cc];
  }
  __syncthreads();
  const size_t ob = (size_t)bh * NHD * NS;
#pragma unroll
  for (int it = 0; it < 2; ++it) {
    const int d = rr + it * 32;
    short o[8];
#pragma unroll
    for (int j = 0; j < 8; ++j) o[j] = tile[cc + j][d];
    *(bf16x8*)&out[ob + (size_t)d * NS + s0 + cc] = *(bf16x8*)o;
  }
}

__device__ __forceinline__ void gload16(const void* g, void* l) {
  __builtin_amdgcn_global_load_lds(
      (const __attribute__((address_space(1))) unsigned int*)g,
      (__attribute__((address_space(3))) unsigned int*)l, 16, 0, 0);
}

// ============ 8-wave 256xBN 8-phase GEMM: C = A(MxK) * Bt(NxK)^T + epilogue ============
// EPI: 0 = plain -> bf16; 1 = +res -> f32; 2 = +bias,gelu -> bf16; 3 = +bias+res -> f32
template <int BN, int EPI>
__global__ __launch_bounds__(512, 2) void gemm8_kernel(
    const short* __restrict__ A, const short* __restrict__ Bt,
    float* __restrict__ Cf, short* __restrict__ Cb,
    const float* __restrict__ bias, const float* __restrict__ res,
    int M, int N, int K) {
  constexpr int NFRAG = BN / 64;           // N-frags per wave (4 or 2)
  constexpr int NJ = NFRAG / 2;            // B-frags per phase
  constexpr int BROUNDS = BN / 64;         // B staging rounds of 8KB
  constexpr int TILE = (256 + BN) * 64;    // shorts per buffer
  __shared__ short lds[2][TILE];           // 128 KiB (BN=256) / 96 KiB (BN=128)

  const int l = threadIdx.x & 63, w = threadIdx.x >> 6;
  const int wm = w >> 2, wn = w & 3;
  const int nbm = M >> 8, nbn = N / BN;
  const int nwg = nbm * nbn;
  int wg = blockIdx.x;
  wg = (wg & 7) * (nwg >> 3) + (wg >> 3);  // XCD swizzle (all grids %8==0)
  const int bm = wg % nbm, bn = wg / nbm;

  // staging: linear LDS dest (row = w*8 + l>>3, phys slot = l&7),
  // pre-swizzled global col slot = (l&7) ^ (row&7)  [m173 pattern]
  const int lrow = w * 8 + (l >> 3);
  const int sgl = (l & 7) ^ ((l >> 3) & 7);
  const short* Ab = A + (size_t)(bm * 256 + lrow) * K + sgl * 8;
  const short* Bb = Bt + (size_t)(bn * BN + lrow) * K + sgl * 8;

  const int fr = l & 15, fg4 = l >> 4;
  f32x4 acc[8][NFRAG] = {};

  // prologue: stage tile 0 -> buf 0
#pragma unroll
  for (int j = 0; j < 4; ++j)
    gload16(Ab + (size_t)j * 64 * K, &lds[0][(j * 64 + w * 8) * 64]);
#pragma unroll
  for (int j = 0; j < BROUNDS; ++j)
    gload16(Bb + (size_t)j * 64 * K, &lds[0][(256 + j * 64 + w * 8) * 64]);

  const int NT = K >> 6;
  int buf = 0;
  for (int t = 0; t < NT; ++t) {
    // tile t's loads (issued >= 1 full tile ago) are the only outstanding ones
    asm volatile("s_waitcnt vmcnt(0)\n\ts_barrier" ::: "memory");
    if (t + 1 < NT) {  // prefetch tile t+1 into other buffer (safe: all reads of it done)
      const short* ga = Ab + (size_t)(t + 1) * 64;
      const short* gb = Bb + (size_t)(t + 1) * 64;
      short* lb = &lds[buf ^ 1][0];
#pragma unroll
      for (int j = 0; j < 4; ++j)
        gload16(ga + (size_t)j * 64 * K, lb + (j * 64 + w * 8) * 64);
#pragma unroll
      for (int j = 0; j < BROUNDS; ++j)
        gload16(gb + (size_t)j * 64 * K, lb + (256 + j * 64 + w * 8) * 64);
    }
    const short* la = &lds[buf][0];
    bf16x8 af[8];
#pragma unroll
    for (int q = 0; q < 4; ++q) {  // 4 phases: (kh, n-half)
      const int kh = q >> 1, np = q & 1;
      if (np == 0) {
#pragma unroll
        for (int mi = 0; mi < 8; ++mi) {
          const int r = wm * 128 + mi * 16 + fr;
          af[mi] = *(const bf16x8*)&la[r * 64 + ((kh * 4 + fg4) ^ (r & 7)) * 8];
        }
      }
      bf16x8 bfr[NJ];
#pragma unroll
      for (int nj = 0; nj < NJ; ++nj) {
        const int r = wn * (BN / 4) + (np * NJ + nj) * 16 + fr;
        bfr[nj] = *(const bf16x8*)&la[(256 + r) * 64 + ((kh * 4 + fg4) ^ (r & 7)) * 8];
      }
      __builtin_amdgcn_s_setprio(1);
#pragma unroll
      for (int mi = 0; mi < 8; ++mi)
#pragma unroll
        for (int nj = 0; nj < NJ; ++nj)
          acc[mi][np * NJ + nj] = __builtin_amdgcn_mfma_f32_16x16x32_bf16(
              af[mi], bfr[nj], acc[mi][np * NJ + nj], 0, 0, 0);
      __builtin_amdgcn_s_setprio(0);
      asm volatile("s_barrier" ::: "memory");
    }
    buf ^= 1;
  }

  // epilogue
  const int fq = (l >> 4) * 4;
  const int wrb = bm * 256 + wm * 128;
  const int wcb = bn * BN + wn * (BN / 4);
#pragma unroll
  for (int mi = 0; mi < 8; ++mi) {
#pragma unroll
    for (int ni = 0; ni < NFRAG; ++ni) {
#pragma unroll
      for (int rr = 0; rr < 4; ++rr) {
        const int row = wrb + mi * 16 + fq + rr;
        const int col = wcb + ni * 16 + fr;
        float v = acc[mi][ni][rr];
        if (EPI == 0) {
          Cb[(size_t)row * N + col] = f2b(v);
        } else if (EPI == 1) {
          Cf[(size_t)row * N + col] = v + res[(size_t)row * N + col];
        } else if (EPI == 2) {
          v += bias[col];
          v = 0.5f * v * (1.0f + erff(v * 0.70710678118f));
          Cb[(size_t)row * N + col] = f2b(v);
        } else {
          Cf[(size_t)row * N + col] = v + bias[col] + res[(size_t)row * N + col];
        }
      }
    }
  }
}

// ---------------- Flash attention (causal), paired q-tiles, QBLK=KBLK=64 ----------------
__device__ __forceinline__ int swz(int row, int col) {
  return row * 64 + (col ^ ((row & 7) << 3));
}

__global__ __launch_bounds__(256, 4) void attn_kernel(
    const short* __restrict__ qkv, const short* __restrict__ vt, short* __restrict__ ctx) {
  __shared__ short Kls[64 * 64];           // [k_local][d], XOR-swizzled
  __shared__ short Vls[64 * 64];           // [d][k_local], XOR-swizzled
  __shared__ short Pls[4][16 * 68];        // per-wave P, pad-68
  const int bid = blockIdx.x;
  const int xcd = bid & 7, idx = bid >> 3;
  const int bh = xcd * 8 + (idx & 7);      // co-locate each (b,h)'s 16 blocks on one XCD
  const int qp = idx >> 3;                 // 0..15
  const int bb = bh >> 4, hh = bh & 15;
  const int lane = threadIdx.x & 63, wave = threadIdx.x >> 6;
  const int fr = lane & 15, fg = lane >> 4;
  const int qt[2] = {qp, 31 - qp};         // paired q-tiles: constant work/block

  bf16x8 qf[2][2];
#pragma unroll
  for (int hf = 0; hf < 2; ++hf) {
    const size_t qb = ((size_t)bb * NS + qt[hf] * 64 + wave * 16 + fr) * QKS + hh * NHD;
    qf[hf][0] = *(const bf16x8*)&qkv[qb + fg * 8];
    qf[hf][1] = *(const bf16x8*)&qkv[qb + 32 + fg * 8];
  }

  f32x4 acc_o[2][4] = {};
  float m_run[2][4], l_run[2][4];
#pragma unroll
  for (int hf = 0; hf < 2; ++hf)
#pragma unroll
    for (int r = 0; r < 4; ++r) { m_run[hf][r] = -INFINITY; l_run[hf][r] = 0.f; }

  const int gcol = ((lane & 7) ^ (lane >> 3)) * 8;
  const int grow = lane >> 3;
  const int nkt = 32 - qp;

  for (int jt = 0; jt < nkt; ++jt) {
    const int k0 = jt * 64;
    __syncthreads();
#pragma unroll
    for (int i = 0; i < 2; ++i) {
      const int c = wave * 2 + i;
      const int r = c * 8 + grow;
      gload16(qkv + ((size_t)bb * NS + k0 + r) * QKS + 1024 + hh * NHD + gcol,
              (char*)Kls + c * 1024);
      gload16(vt + ((size_t)bh * NHD + r) * NS + k0 + gcol, (char*)Vls + c * 1024);
    }
    __syncthreads();

#pragma unroll
    for (int hf = 0; hf < 2; ++hf) {
      if (hf == 0 && jt > qp) continue;
      const bool diag = (jt == qt[hf]);
      f32x4 s[4] = {};
#pragma unroll
      for (int kk = 0; kk < 2; ++kk) {
        const bf16x8 af = qf[hf][kk];
#pragma unroll
        for (int ni = 0; ni < 4; ++ni) {
          const bf16x8 bf = *(const bf16x8*)&Kls[swz(ni * 16 + fr, kk * 32 + fg * 8)];
          s[ni] = __builtin_amdgcn_mfma_f32_16x16x32_bf16(af, bf, s[ni], 0, 0, 0);
        }
      }
      float mt[4] = {-INFINITY, -INFINITY, -INFINITY, -INFINITY};
#pragma unroll
      for (int ni = 0; ni < 4; ++ni) {
#pragma unroll
        for (int rr = 0; rr < 4; ++rr) {
          float val = s[ni][rr] * 0.125f;
          if (diag && (ni * 16 + fr > wave * 16 + fg * 4 + rr)) val = -INFINITY;
          s[ni][rr] = val;
          mt[rr] = fmaxf(mt[rr], val);
        }
      }
#pragma unroll
      for (int m = 1; m < 16; m <<= 1) {
#pragma unroll
        for (int rr = 0; rr < 4; ++rr) mt[rr] = fmaxf(mt[rr], __shfl_xor(mt[rr], m));
      }
      float sc_f[4];
#pragma unroll
      for (int rr = 0; rr < 4; ++rr) {
        const float mn = fmaxf(m_run[hf][rr], mt[rr]);
        sc_f[rr] = __expf(m_run[hf][rr] - mn);
        m_run[hf][rr] = mn;
      }
      float lt[4] = {0.f, 0.f, 0.f, 0.f};
#pragma unroll
      for (int ni = 0; ni < 4; ++ni) {
#pragma unroll
        for (int rr = 0; rr < 4; ++rr) {
          const float p = __expf(s[ni][rr] - m_run[hf][rr]);
          s[ni][rr] = p;
          lt[rr] += p;
        }
      }
#pragma unroll
      for (int m = 1; m < 16; m <<= 1) {
#pragma unroll
        for (int rr = 0; rr < 4; ++rr) lt[rr] += __shfl_xor(lt[rr], m);
      }
#pragma unroll
      for (int rr = 0; rr < 4; ++rr) l_run[hf][rr] = l_run[hf][rr] * sc_f[rr] + lt[rr];
#pragma unroll
      for (int di = 0; di < 4; ++di) {
#pragma unroll
        for (int rr = 0; rr < 4; ++rr) acc_o[hf][di][rr] *= sc_f[rr];
      }
#pragma unroll
      for (int ni = 0; ni < 4; ++ni) {
#pragma unroll
        for (int rr = 0; rr < 4; ++rr)
          Pls[wave][(fg * 4 + rr) * 68 + ni * 16 + fr] = f2b(s[ni][rr]);
      }
#pragma unroll
      for (int kk = 0; kk < 2; ++kk) {
        const short4v p0 = *(const short4v*)&Pls[wave][fr * 68 + kk * 32 + fg * 8];
        const short4v p1 = *(const short4v*)&Pls[wave][fr * 68 + kk * 32 + fg * 8 + 4];
        const bf16x8 pf = __builtin_shufflevector(p0, p1, 0, 1, 2, 3, 4, 5, 6, 7);
#pragma unroll
        for (int di = 0; di < 4; ++di) {
          const bf16x8 vf = *(const bf16x8*)&Vls[swz(di * 16 + fr, kk * 32 + fg * 8)];
          acc_o[hf][di] = __builtin_amdgcn_mfma_f32_16x16x32_bf16(pf, vf, acc_o[hf][di], 0, 0, 0);
        }
      }
    }
  }

#pragma unroll
  for (int hf = 0; hf < 2; ++hf) {
    const size_t ob = ((size_t)bb * NS + qt[hf] * 64) * ND + hh * NHD;
#pragma unroll
    for (int di = 0; di < 4; ++di) {
#pragma unroll
      for (int rr = 0; rr < 4; ++rr) {
        const int row = wave * 16 + fg * 4 + rr;
        const int col = di * 16 + fr;
        ctx[ob + (size_t)row * ND + col] = f2b(acc_o[hf][di][rr] / l_run[hf][rr]);
      }
    }
  }
}

extern "C" void kernel_launch(void* const* d_in, const int* in_sizes, int n_in,
                              void* d_out, int out_size, void* d_ws, size_t ws_size,
                              hipStream_t stream) {
  (void)in_sizes; (void)n_in; (void)out_size; (void)ws_size;
  const float* x     = (const float*)d_in[0];
  const float* ln1_g = (const float*)d_in[1];
  const float* ln1_b = (const float*)d_in[2];
  const float* Wq    = (const float*)d_in[3];
  const float* Wk    = (const float*)d_in[4];
  const float* Wv    = (const float*)d_in[5];
  const float* Wo    = (const float*)d_in[6];
  const float* ln2_g = (const float*)d_in[7];
  const float* ln2_b = (const float*)d_in[8];
  const float* W1    = (const float*)d_in[9];
  const float* b1    = (const float*)d_in[10];
  const float* W2    = (const float*)d_in[11];
  const float* b2    = (const float*)d_in[12];
  float* out = (float*)d_out;

  char* ws = (char*)d_ws;
  const size_t MiB = 1024 * 1024;
  short* wqkvT = (short*)(ws + 0 * MiB);   // 6 MiB: [3072][1024] packed q|k|v
  short* woT   = (short*)(ws + 6 * MiB);   // 2 MiB
  short* w1T   = (short*)(ws + 8 * MiB);   // 8 MiB
  short* w2T   = (short*)(ws + 16 * MiB);  // 8 MiB
  short* h     = (short*)(ws + 24 * MiB);  // 16 MiB: LN out; ctx reuses after h dead
  short* ctx   = (short*)(ws + 24 * MiB);  //   (attn out; consumed by Wo before LN2 rewrites h)
  short* qkv   = (short*)(ws + 40 * MiB);  // 48 MiB: [8192][3072]
  short* vt    = (short*)(ws + 88 * MiB);  // 16 MiB: V^T [64][64][2048]
  short* hff   = (short*)(ws + 40 * MiB);  // 64 MiB: reuses qkv+vt after attention
  float* x1    = (float*)(ws + 104 * MiB); // 32 MiB; end = 136 MiB

  // weight transpose-casts (B^T layout, bf16); q|k|v packed into one [3072][1024]
  tcast_kernel<<<dim3(32, 32), 256, 0, stream>>>(Wq, wqkvT, 1024, 1024);
  tcast_kernel<<<dim3(32, 32), 256, 0, stream>>>(Wk, wqkvT + 1024 * 1024, 1024, 1024);
  tcast_kernel<<<dim3(32, 32), 256, 0, stream>>>(Wv, wqkvT + 2048 * 1024, 1024, 1024);
  tcast_kernel<<<dim3(32, 32), 256, 0, stream>>>(Wo, woT, 1024, 1024);
  tcast_kernel<<<dim3(128, 32), 256, 0, stream>>>(W1, w1T, 1024, 4096);
  tcast_kernel<<<dim3(32, 128), 256, 0, stream>>>(W2, w2T, 4096, 1024);

  // LN1
  ln_kernel<<<8192, 256, 0, stream>>>(x, ln1_g, ln1_b, h);

  // fused QKV projection: [8192][3072]
  gemm8_kernel<256, 0><<<384, 512, 0, stream>>>(h, wqkvT, nullptr, qkv, nullptr, nullptr,
                                                8192, 3072, 1024);
  vtrans_kernel<<<dim3(32, 64), 256, 0, stream>>>(qkv, vt);

  // causal flash attention
  attn_kernel<<<1024, 256, 0, stream>>>(qkv, vt, ctx);

  // out-proj + residual -> x1 (f32)
  gemm8_kernel<128, 1><<<256, 512, 0, stream>>>(ctx, woT, x1, nullptr, nullptr, x,
                                                8192, 1024, 1024);

  // LN2
  ln_kernel<<<8192, 256, 0, stream>>>(x1, ln2_g, ln2_b, h);

  // FFN
  gemm8_kernel<256, 2><<<512, 512, 0, stream>>>(h, w1T, nullptr, hff, b1, nullptr,
                                                8192, 4096, 1024);
  gemm8_kernel<128, 3><<<256, 512, 0, stream>>>(hff, w2T, out, nullptr, b2, x1,
                                                8192, 1024, 4096);
}

// Round 5
// 406.762 us; speedup vs baseline: 1.6506x; 1.0785x over previous
//
#include <hip/hip_runtime.h>
#include <hip/hip_bf16.h>
#include <math.h>

#define NB 4
#define NS 2048
#define ND 1024
#define NH 16
#define NHD 64
#define NDFF 4096
#define QKS 3072   // packed qkv row stride

typedef __attribute__((ext_vector_type(8))) short bf16x8;
typedef __attribute__((ext_vector_type(4))) float f32x4;
typedef __attribute__((ext_vector_type(16))) float f32x16;
typedef __attribute__((ext_vector_type(4))) short short4v;
typedef __attribute__((ext_vector_type(4))) int i32x4;

static __device__ __forceinline__ short f2b(float f) {
  union { __hip_bfloat16 b; short s; } u;
  u.b = __float2bfloat16(f);
  return u.s;
}

static __device__ __forceinline__ int cvtpk(float lo, float hi_) {
  int r;
  asm("v_cvt_pk_bf16_f32 %0, %1, %2" : "=v"(r) : "v"(lo), "v"(hi_));
  return r;
}

// pair (lane, lane^32) max / sum via permlane32_swap builtin (returns both results;
// r[0]/r[1] are {a@low,b@low} / {a@high,b@high} per pair -> order-independent reduce)
static __device__ __forceinline__ float pairmax(float x) {
  auto r = __builtin_amdgcn_permlane32_swap(__float_as_uint(x), __float_as_uint(x), false, false);
  return fmaxf(__uint_as_float(r[0]), __uint_as_float(r[1]));
}
static __device__ __forceinline__ float pairsum(float x) {
  auto r = __builtin_amdgcn_permlane32_swap(__float_as_uint(x), __float_as_uint(x), false, false);
  return __uint_as_float(r[0]) + __uint_as_float(r[1]);
}

// ---------------- LayerNorm: f32 in -> bf16 out ----------------
__global__ __launch_bounds__(256) void ln_kernel(
    const float* __restrict__ x, const float* __restrict__ g,
    const float* __restrict__ b, short* __restrict__ out) {
  __shared__ float red[8];
  const int row = blockIdx.x;
  const int t = threadIdx.x;
  const float* xr = x + (size_t)row * ND;
  const float4 xv = *(const float4*)(xr + t * 4);
  float s = xv.x + xv.y + xv.z + xv.w;
  float ss = xv.x * xv.x + xv.y * xv.y + xv.z * xv.z + xv.w * xv.w;
#pragma unroll
  for (int m = 32; m >= 1; m >>= 1) {
    s += __shfl_xor(s, m);
    ss += __shfl_xor(ss, m);
  }
  if ((t & 63) == 0) { red[(t >> 6) * 2] = s; red[(t >> 6) * 2 + 1] = ss; }
  __syncthreads();
  s = red[0] + red[2] + red[4] + red[6];
  ss = red[1] + red[3] + red[5] + red[7];
  const float mu = s * (1.0f / ND);
  const float var = ss * (1.0f / ND) - mu * mu;
  const float rs = rsqrtf(var + 1e-5f);
  const float4 gv = *(const float4*)(g + t * 4);
  const float4 bv = *(const float4*)(b + t * 4);
  short o[4];
  o[0] = f2b((xv.x - mu) * rs * gv.x + bv.x);
  o[1] = f2b((xv.y - mu) * rs * gv.y + bv.y);
  o[2] = f2b((xv.z - mu) * rs * gv.z + bv.z);
  o[3] = f2b((xv.w - mu) * rs * gv.w + bv.w);
  *(short4v*)(out + (size_t)row * ND + t * 4) = *(short4v*)o;
}

// ------------- transpose + cast: in f32 (K x N) -> out bf16 (N x K) -------------
__global__ __launch_bounds__(256) void tcast_kernel(
    const float* __restrict__ in, short* __restrict__ out, int K, int N) {
  __shared__ float tile[32][33];
  const int n0 = blockIdx.x * 32, k0 = blockIdx.y * 32;
  const int tx = threadIdx.x & 31, ty = threadIdx.x >> 5;  // 32 x 8
#pragma unroll
  for (int i = 0; i < 32; i += 8)
    tile[ty + i][tx] = in[(size_t)(k0 + ty + i) * N + n0 + tx];
  __syncthreads();
#pragma unroll
  for (int i = 0; i < 32; i += 8)
    out[(size_t)(n0 + ty + i) * K + k0 + tx] = f2b(tile[tx][ty + i]);
}

// ------------- V transpose: packed qkv (v at col 2048) -> vt[b*H+h][d][s] bf16 -------------
__global__ __launch_bounds__(256) void vtrans_kernel(
    const short* __restrict__ in, short* __restrict__ out) {
  __shared__ short tile[64][72];
  const int s0 = blockIdx.x * 64, bh = blockIdx.y;
  const int bb = bh >> 4, hh = bh & 15;
  const int rr = threadIdx.x >> 3, cc = (threadIdx.x & 7) * 8;  // rr 0..31
#pragma unroll
  for (int it = 0; it < 2; ++it) {
    const int r = rr + it * 32;
    *(bf16x8*)&tile[r][cc] =
        *(const bf16x8*)&in[((size_t)(bb * NS + s0 + r)) * QKS + 2048 + hh * NHD + cc];
  }
  __syncthreads();
  const size_t ob = (size_t)bh * NHD * NS;
#pragma unroll
  for (int it = 0; it < 2; ++it) {
    const int d = rr + it * 32;
    short o[8];
#pragma unroll
    for (int j = 0; j < 8; ++j) o[j] = tile[cc + j][d];
    *(bf16x8*)&out[ob + (size_t)d * NS + s0 + cc] = *(bf16x8*)o;
  }
}

__device__ __forceinline__ void gload16(const void* g, void* l) {
  __builtin_amdgcn_global_load_lds(
      (const __attribute__((address_space(1))) unsigned int*)g,
      (__attribute__((address_space(3))) unsigned int*)l, 16, 0, 0);
}

// ============ 8-wave 256xBN 8-phase GEMM: C = A(MxK) * Bt(NxK)^T + epilogue ============
// EPI: 0 = plain -> bf16; 1 = +res -> f32; 2 = +bias,gelu -> bf16; 3 = +bias+res -> f32
template <int BN, int EPI>
__global__ __launch_bounds__(512, 2) void gemm8_kernel(
    const short* __restrict__ A, const short* __restrict__ Bt,
    float* __restrict__ Cf, short* __restrict__ Cb,
    const float* __restrict__ bias, const float* __restrict__ res,
    int M, int N, int K) {
  constexpr int NFRAG = BN / 64;           // N-frags per wave (4 or 2)
  constexpr int NJ = NFRAG / 2;            // B-frags per phase
  constexpr int BROUNDS = BN / 64;         // B staging rounds of 8KB
  constexpr int TILE = (256 + BN) * 64;    // shorts per buffer
  __shared__ short lds[2][TILE];           // 128 KiB (BN=256) / 96 KiB (BN=128)

  const int l = threadIdx.x & 63, w = threadIdx.x >> 6;
  const int wm = w >> 2, wn = w & 3;
  const int nbm = M >> 8, nbn = N / BN;
  const int nwg = nbm * nbn;
  int wg = blockIdx.x;
  wg = (wg & 7) * (nwg >> 3) + (wg >> 3);  // XCD swizzle (all grids %8==0)
  const int bm = wg % nbm, bn = wg / nbm;

  // staging: linear LDS dest (row = w*8 + l>>3, phys slot = l&7),
  // pre-swizzled global col slot = (l&7) ^ (row&7)
  const int lrow = w * 8 + (l >> 3);
  const int sgl = (l & 7) ^ ((l >> 3) & 7);
  const short* Ab = A + (size_t)(bm * 256 + lrow) * K + sgl * 8;
  const short* Bb = Bt + (size_t)(bn * BN + lrow) * K + sgl * 8;

  const int fr = l & 15, fg4 = l >> 4;
  f32x4 acc[8][NFRAG] = {};

  // prologue: stage tile 0 -> buf 0
#pragma unroll
  for (int j = 0; j < 4; ++j)
    gload16(Ab + (size_t)j * 64 * K, &lds[0][(j * 64 + w * 8) * 64]);
#pragma unroll
  for (int j = 0; j < BROUNDS; ++j)
    gload16(Bb + (size_t)j * 64 * K, &lds[0][(256 + j * 64 + w * 8) * 64]);

  const int NT = K >> 6;
  int buf = 0;
  for (int t = 0; t < NT; ++t) {
    asm volatile("s_waitcnt vmcnt(0)\n\ts_barrier" ::: "memory");
    if (t + 1 < NT) {
      const short* ga = Ab + (size_t)(t + 1) * 64;
      const short* gb = Bb + (size_t)(t + 1) * 64;
      short* lb = &lds[buf ^ 1][0];
#pragma unroll
      for (int j = 0; j < 4; ++j)
        gload16(ga + (size_t)j * 64 * K, lb + (j * 64 + w * 8) * 64);
#pragma unroll
      for (int j = 0; j < BROUNDS; ++j)
        gload16(gb + (size_t)j * 64 * K, lb + (256 + j * 64 + w * 8) * 64);
    }
    const short* la = &lds[buf][0];
    bf16x8 af[8];
#pragma unroll
    for (int q = 0; q < 4; ++q) {  // 4 phases: (kh, n-half)
      const int kh = q >> 1, np = q & 1;
      if (np == 0) {
#pragma unroll
        for (int mi = 0; mi < 8; ++mi) {
          const int r = wm * 128 + mi * 16 + fr;
          af[mi] = *(const bf16x8*)&la[r * 64 + ((kh * 4 + fg4) ^ (r & 7)) * 8];
        }
      }
      bf16x8 bfr[NJ];
#pragma unroll
      for (int nj = 0; nj < NJ; ++nj) {
        const int r = wn * (BN / 4) + (np * NJ + nj) * 16 + fr;
        bfr[nj] = *(const bf16x8*)&la[(256 + r) * 64 + ((kh * 4 + fg4) ^ (r & 7)) * 8];
      }
      __builtin_amdgcn_s_setprio(1);
#pragma unroll
      for (int mi = 0; mi < 8; ++mi)
#pragma unroll
        for (int nj = 0; nj < NJ; ++nj)
          acc[mi][np * NJ + nj] = __builtin_amdgcn_mfma_f32_16x16x32_bf16(
              af[mi], bfr[nj], acc[mi][np * NJ + nj], 0, 0, 0);
      __builtin_amdgcn_s_setprio(0);
      asm volatile("s_barrier" ::: "memory");
    }
    buf ^= 1;
  }

  // epilogue
  const int fq = (l >> 4) * 4;
  const int wrb = bm * 256 + wm * 128;
  const int wcb = bn * BN + wn * (BN / 4);
#pragma unroll
  for (int mi = 0; mi < 8; ++mi) {
#pragma unroll
    for (int ni = 0; ni < NFRAG; ++ni) {
#pragma unroll
      for (int rr = 0; rr < 4; ++rr) {
        const int row = wrb + mi * 16 + fq + rr;
        const int col = wcb + ni * 16 + fr;
        float v = acc[mi][ni][rr];
        if (EPI == 0) {
          Cb[(size_t)row * N + col] = f2b(v);
        } else if (EPI == 1) {
          Cf[(size_t)row * N + col] = v + res[(size_t)row * N + col];
        } else if (EPI == 2) {
          v += bias[col];
          v = 0.5f * v * (1.0f + erff(v * 0.70710678118f));
          Cb[(size_t)row * N + col] = f2b(v);
        } else {
          Cf[(size_t)row * N + col] = v + bias[col] + res[(size_t)row * N + col];
        }
      }
    }
  }
}

// ======= Flash attention (causal), swapped-operand 32x32 MFMA, in-register softmax =======
// 4 waves; each wave owns 32 queries of chunk A (cp) and 32 of chunk B (15-cp).
// S^T = mfma(K, Q^T): lane = one query column; row-reduce = in-register + permlane32_swap.
__global__ __launch_bounds__(256, 2) void attn_kernel(
    const short* __restrict__ qkv, const short* __restrict__ vt, short* __restrict__ ctx) {
  __shared__ short Kls[2][64 * 64];   // [key][d], XOR-swizzled, double-buffered
  __shared__ short Vls[2][64 * 64];   // [d][key] (V^T tile), XOR-swizzled

  const int bid = blockIdx.x;
  const int bh = (bid & 7) * 8 + ((bid >> 3) & 7);  // XCD-colocated heads
  const int cp = bid >> 6;                          // chunk pair 0..7
  const int bb = bh >> 4, hh = bh & 15;
  const int lane = threadIdx.x & 63, wave = threadIdx.x >> 6;
  const int ql = lane & 31, hi = lane >> 5;
  const int qbA = cp * 128 + wave * 32;
  const int qbB = (15 - cp) * 128 + wave * 32;

  // Q fragments in registers: lane holds Q[qb+ql][st*16 + hi*8 .. +7]
  bf16x8 qf[2][4];
#pragma unroll
  for (int hf = 0; hf < 2; ++hf) {
    const int qb0 = hf ? qbB : qbA;
    const size_t qrow = ((size_t)bb * NS + qb0 + ql) * QKS + hh * NHD;
#pragma unroll
    for (int st = 0; st < 4; ++st)
      qf[hf][st] = *(const bf16x8*)&qkv[qrow + st * 16 + hi * 8];
  }

  f32x16 acc[2][2] = {};          // [half][dblk]: O^T fragments
  float m_run[2] = {-1e37f, -1e37f};
  float l_run[2] = {0.f, 0.f};

  // staging geometry (pre-swizzled global source, linear LDS dest)
  const int srow = lane >> 3;
  const int sslot = (lane & 7) ^ srow;
  const short* kbasep = qkv + (size_t)bb * NS * QKS + 1024 + hh * NHD + sslot * 8;
  const short* vbasep = vt + (size_t)bh * NHD * NS + sslot * 8;

  const int nkt = (16 - cp) * 2;
  // prologue: stage tile 0
#pragma unroll
  for (int r = 0; r < 2; ++r) {
    const int row = r * 32 + wave * 8 + srow;
    gload16(kbasep + (size_t)row * QKS, &Kls[0][(r * 32 + wave * 8) * 64]);
    gload16(vbasep + (size_t)row * NS, &Vls[0][(r * 32 + wave * 8) * 64]);
  }

  int buf = 0;
  for (int jt = 0; jt < nkt; ++jt) {
    asm volatile("s_waitcnt vmcnt(0)\n\ts_barrier" ::: "memory");
    if (jt + 1 < nkt) {
      const int k0n = (jt + 1) * 64;
#pragma unroll
      for (int r = 0; r < 2; ++r) {
        const int row = r * 32 + wave * 8 + srow;
        gload16(kbasep + (size_t)(k0n + row) * QKS, &Kls[buf ^ 1][(r * 32 + wave * 8) * 64]);
        gload16(vbasep + (size_t)row * NS + k0n, &Vls[buf ^ 1][(r * 32 + wave * 8) * 64]);
      }
    }
    const int k0 = jt * 64;
    const short* Kb = &Kls[buf][0];
    const short* Vb = &Vls[buf][0];
#pragma unroll
    for (int ks = 0; ks < 2; ++ks) {
      const int kbase = k0 + ks * 32;
      if (kbase > qbB) continue;  // wave-uniform: no half active
      // fragment preloads (shared by both halves)
      bf16x8 kf[4], vf[2][2];
      const int krow = ks * 32 + ql;
#pragma unroll
      for (int st = 0; st < 4; ++st)
        kf[st] = *(const bf16x8*)&Kb[krow * 64 + ((st * 2 + hi) ^ (krow & 7)) * 8];
#pragma unroll
      for (int db = 0; db < 2; ++db) {
        const int vrow = db * 32 + ql;
#pragma unroll
        for (int su = 0; su < 2; ++su)
          vf[db][su] =
              *(const bf16x8*)&Vb[vrow * 64 + ((ks * 4 + su * 2 + hi) ^ (vrow & 7)) * 8];
      }
#pragma unroll
      for (int hf = 0; hf < 2; ++hf) {
        const int qb0 = hf ? qbB : qbA;
        if (kbase > qb0) continue;  // wave-uniform skip
        const int qg = qb0 + ql;
        f32x16 s = {};
        __builtin_amdgcn_s_setprio(1);
#pragma unroll
        for (int st = 0; st < 4; ++st)
          s = __builtin_amdgcn_mfma_f32_32x32x16_bf16(kf[st], qf[hf][st], s, 0, 0, 0);
        __builtin_amdgcn_s_setprio(0);
        // ---- softmax (per-lane query column) ----
        const bool masked = (kbase + 31 > qb0);
        float pv[16];
        float mt = -INFINITY;
#pragma unroll
        for (int r = 0; r < 16; ++r) {
          float v = s[r] * 0.125f;
          if (masked) {
            const int key = kbase + 4 * hi + (r & 3) + 8 * (r >> 2);
            v = (key > qg) ? -INFINITY : v;
          }
          pv[r] = v;
          mt = fmaxf(mt, v);
        }
        mt = pairmax(mt);                       // full row max (pair lane^32)
        if (!__all(mt - m_run[hf] <= 8.0f)) {   // defer-max (T13)
          const float mn = fmaxf(m_run[hf], mt);
          const float sc = __expf(m_run[hf] - mn);
          m_run[hf] = mn;
          l_run[hf] *= sc;
          acc[hf][0] *= sc;
          acc[hf][1] *= sc;
        }
        float pe[16];
        float lt = 0.f;
#pragma unroll
        for (int r = 0; r < 16; ++r) {
          pe[r] = __expf(fminf(pv[r] - m_run[hf], 80.0f));  // clamp: never INF
          lt += pe[r];
        }
        l_run[hf] += pairsum(lt);
        // ---- P -> bf16 B-fragments (cvt_pk + permlane32_swap, T12/HK recipe) ----
        bf16x8 pf[2];
#pragma unroll
        for (int su = 0; su < 2; ++su) {
          const int a0 = cvtpk(pe[su * 8 + 0], pe[su * 8 + 1]);
          const int a1 = cvtpk(pe[su * 8 + 2], pe[su * 8 + 3]);
          const int b0 = cvtpk(pe[su * 8 + 4], pe[su * 8 + 5]);
          const int b1 = cvtpk(pe[su * 8 + 6], pe[su * 8 + 7]);
          auto r0 = __builtin_amdgcn_permlane32_swap((unsigned)a0, (unsigned)b0, false, false);
          auto r1 = __builtin_amdgcn_permlane32_swap((unsigned)a1, (unsigned)b1, false, false);
          union { i32x4 w; bf16x8 v; } u;
          u.w[0] = r0[0]; u.w[1] = r1[0]; u.w[2] = r0[1]; u.w[3] = r1[1];
          pf[su] = u.v;
        }
        __builtin_amdgcn_s_setprio(1);
#pragma unroll
        for (int su = 0; su < 2; ++su) {
          acc[hf][0] = __builtin_amdgcn_mfma_f32_32x32x16_bf16(vf[0][su], pf[su], acc[hf][0], 0, 0, 0);
          acc[hf][1] = __builtin_amdgcn_mfma_f32_32x32x16_bf16(vf[1][su], pf[su], acc[hf][1], 0, 0, 0);
        }
        __builtin_amdgcn_s_setprio(0);
      }
    }
    asm volatile("s_waitcnt lgkmcnt(0)\n\ts_barrier" ::: "memory");
    buf ^= 1;
  }

  // ---- epilogue: O = O^T/l, cvt_pk + permlane back to row layout, 16B stores ----
#pragma unroll
  for (int hf = 0; hf < 2; ++hf) {
    const int qb0 = hf ? qbB : qbA;
    const float inv = 1.0f / l_run[hf];
    const size_t ob = ((size_t)bb * NS + qb0 + ql) * ND + hh * NHD + hi * 8;
#pragma unroll
    for (int db = 0; db < 2; ++db) {
#pragma unroll
      for (int J = 0; J < 2; ++J) {
        const int a0 = cvtpk(acc[hf][db][J * 8 + 0] * inv, acc[hf][db][J * 8 + 1] * inv);
        const int a1 = cvtpk(acc[hf][db][J * 8 + 2] * inv, acc[hf][db][J * 8 + 3] * inv);
        const int b0 = cvtpk(acc[hf][db][J * 8 + 4] * inv, acc[hf][db][J * 8 + 5] * inv);
        const int b1 = cvtpk(acc[hf][db][J * 8 + 6] * inv, acc[hf][db][J * 8 + 7] * inv);
        auto r0 = __builtin_amdgcn_permlane32_swap((unsigned)a0, (unsigned)b0, false, false);
        auto r1 = __builtin_amdgcn_permlane32_swap((unsigned)a1, (unsigned)b1, false, false);
        union { i32x4 w; bf16x8 v; } u;
        u.w[0] = r0[0]; u.w[1] = r1[0]; u.w[2] = r0[1]; u.w[3] = r1[1];
        *(bf16x8*)&ctx[ob + db * 32 + J * 16] = u.v;
      }
    }
  }
}

extern "C" void kernel_launch(void* const* d_in, const int* in_sizes, int n_in,
                              void* d_out, int out_size, void* d_ws, size_t ws_size,
                              hipStream_t stream) {
  (void)in_sizes; (void)n_in; (void)out_size; (void)ws_size;
  const float* x     = (const float*)d_in[0];
  const float* ln1_g = (const float*)d_in[1];
  const float* ln1_b = (const float*)d_in[2];
  const float* Wq    = (const float*)d_in[3];
  const float* Wk    = (const float*)d_in[4];
  const float* Wv    = (const float*)d_in[5];
  const float* Wo    = (const float*)d_in[6];
  const float* ln2_g = (const float*)d_in[7];
  const float* ln2_b = (const float*)d_in[8];
  const float* W1    = (const float*)d_in[9];
  const float* b1    = (const float*)d_in[10];
  const float* W2    = (const float*)d_in[11];
  const float* b2    = (const float*)d_in[12];
  float* out = (float*)d_out;

  char* ws = (char*)d_ws;
  const size_t MiB = 1024 * 1024;
  short* wqkvT = (short*)(ws + 0 * MiB);   // 6 MiB: [3072][1024] packed q|k|v
  short* woT   = (short*)(ws + 6 * MiB);   // 2 MiB
  short* w1T   = (short*)(ws + 8 * MiB);   // 8 MiB
  short* w2T   = (short*)(ws + 16 * MiB);  // 8 MiB
  short* h     = (short*)(ws + 24 * MiB);  // 16 MiB: LN out; ctx reuses after h dead
  short* ctx   = (short*)(ws + 24 * MiB);
  short* qkv   = (short*)(ws + 40 * MiB);  // 48 MiB: [8192][3072]
  short* vt    = (short*)(ws + 88 * MiB);  // 16 MiB: V^T [64][64][2048]
  short* hff   = (short*)(ws + 40 * MiB);  // 64 MiB: reuses qkv+vt after attention
  float* x1    = (float*)(ws + 104 * MiB); // 32 MiB; end = 136 MiB

  // weight transpose-casts (B^T layout, bf16); q|k|v packed into one [3072][1024]
  tcast_kernel<<<dim3(32, 32), 256, 0, stream>>>(Wq, wqkvT, 1024, 1024);
  tcast_kernel<<<dim3(32, 32), 256, 0, stream>>>(Wk, wqkvT + 1024 * 1024, 1024, 1024);
  tcast_kernel<<<dim3(32, 32), 256, 0, stream>>>(Wv, wqkvT + 2048 * 1024, 1024, 1024);
  tcast_kernel<<<dim3(32, 32), 256, 0, stream>>>(Wo, woT, 1024, 1024);
  tcast_kernel<<<dim3(128, 32), 256, 0, stream>>>(W1, w1T, 1024, 4096);
  tcast_kernel<<<dim3(32, 128), 256, 0, stream>>>(W2, w2T, 4096, 1024);

  // LN1
  ln_kernel<<<8192, 256, 0, stream>>>(x, ln1_g, ln1_b, h);

  // fused QKV projection: [8192][3072]
  gemm8_kernel<256, 0><<<384, 512, 0, stream>>>(h, wqkvT, nullptr, qkv, nullptr, nullptr,
                                                8192, 3072, 1024);
  vtrans_kernel<<<dim3(32, 64), 256, 0, stream>>>(qkv, vt);

  // causal flash attention (swapped-operand 32x32, paired chunks, XCD-colocated)
  attn_kernel<<<512, 256, 0, stream>>>(qkv, vt, ctx);

  // out-proj + residual -> x1 (f32)
  gemm8_kernel<128, 1><<<256, 512, 0, stream>>>(ctx, woT, x1, nullptr, nullptr, x,
                                                8192, 1024, 1024);

  // LN2
  ln_kernel<<<8192, 256, 0, stream>>>(x1, ln2_g, ln2_b, h);

  // FFN
  gemm8_kernel<256, 2><<<512, 512, 0, stream>>>(h, w1T, nullptr, hff, b1, nullptr,
                                                8192, 4096, 1024);
  gemm8_kernel<128, 3><<<256, 512, 0, stream>>>(hff, w2T, out, nullptr, b2, x1,
                                                8192, 1024, 4096);
}